// Round 7
// baseline (223.171 us; speedup 1.0000x reference)
//
#include <hip/hip_runtime.h>
#include <stdint.h>
#include <math.h>

typedef unsigned int u32;
typedef unsigned long long u64;

#define E_CNT   8192
#define N_CNT   4096
#define TOT_N   (1u << 26)     // E*E elements, one threefry eval each (partitionable)
#define OUT_K   16384          // K*E = 2*8192
#define NODE_BM_WORDS 128      // 4096 bits / 32
#define N_BLKS  8192           // sample blocks; each covers 8192 elements

// ---- workspace layout (bytes) ----
#define OFF_BAD      0x000000  // u32[4096*128]  2 MiB  bad-bitmap per node
#define OFF_CNT_DST  0x200000  // u32[4096]
#define OFF_CNT_SRC  0x204000  // u32[4096]
#define OFF_SCALARS  0x208000  // [0]=num_neg [1]=done ticket [2]=T9 [3]=block ticket
#define OFF_DESC     0x210000  // u64[8192] lookback descriptors (flag<<32 | count)
#define ZERO_BYTES   0x220000  // zero everything above (2.125 MiB)

// rotl as a single v_alignbit_b32: alignbit(x,x,32-d) = (x>>(32-d))|(x<<d)
__device__ __forceinline__ u32 rotl32(u32 x, u32 d) {
  return __builtin_amdgcn_alignbit(x, x, 32u - d);
}

// prefix popcount of 64-bit mask below this lane
__device__ __forceinline__ u32 mbcnt64(u64 m) {
  return __builtin_amdgcn_mbcnt_hi((u32)(m >> 32),
         __builtin_amdgcn_mbcnt_lo((u32)m, 0u));
}

// FOUR interleaved JAX threefry2x32 evals, key=(0,42), counters (0,ia)..(0,id).
// Partitionable mode: per-element counter = flat index, bits = o0 ^ o1.
__device__ __forceinline__ void threefry4_0_42(u32 ia, u32 ib, u32 ic, u32 id,
                                               u32& ra, u32& rb, u32& rc, u32& rd) {
  const u32 k1 = 42u, k2 = 0x1BD11BF0u; // 0 ^ 42 ^ 0x1BD11BDA
  u32 A0 = 0u, A1 = ia + k1;
  u32 B0 = 0u, B1 = ib + k1;
  u32 C0 = 0u, C1 = ic + k1;
  u32 D0 = 0u, D1 = id + k1;
#define R4(r) { A0 += A1; B0 += B1; C0 += C1; D0 += D1; \
  A1 = rotl32(A1, r); B1 = rotl32(B1, r); C1 = rotl32(C1, r); D1 = rotl32(D1, r); \
  A1 ^= A0; B1 ^= B0; C1 ^= C0; D1 ^= D0; }
#define INJ(c0, c1) { A0 += (c0); B0 += (c0); C0 += (c0); D0 += (c0); \
  A1 += (c1); B1 += (c1); C1 += (c1); D1 += (c1); }
#define INJ1(c1) { A1 += (c1); B1 += (c1); C1 += (c1); D1 += (c1); }
  R4(13) R4(15) R4(26) R4(6)
  INJ(k1, k2 + 1u)
  R4(17) R4(29) R4(16) R4(24)
  INJ(k2, 2u)
  R4(13) R4(15) R4(26) R4(6)
  INJ1(k1 + 3u)
  R4(17) R4(29) R4(16) R4(24)
  INJ(k1, k2 + 4u)
  R4(13) R4(15) R4(26) R4(6)
  INJ(k2, 5u)
#undef R4
#undef INJ
#undef INJ1
  ra = A0 ^ A1;
  rb = B0 ^ B1;
  rc = C0 ^ C1;
  rd = D0 ^ D1;
}

// --- K1: bad bitmap + histograms ---
__global__ void k_build(const int* __restrict__ src, const int* __restrict__ dst,
                        u32* __restrict__ bad, u32* __restrict__ cnt_dst,
                        u32* __restrict__ cnt_src) {
  int tid = blockIdx.x * 256 + threadIdx.x;   // < 8192
  if (tid < N_CNT) {
    atomicOr(&bad[(u32)tid * NODE_BM_WORDS + ((u32)tid >> 5)], 1u << (tid & 31));
  }
  u32 s = (u32)src[tid], d = (u32)dst[tid];
  atomicOr(&bad[s * NODE_BM_WORDS + (d >> 5)], 1u << (d & 31));
  atomicAdd(&cnt_dst[d], 1u);
  atomicAdd(&cnt_src[s], 1u);
}

// --- K2: num_negatives + fused threshold epilogue (last-block-done) ---
__global__ void __launch_bounds__(1024) k_rowcount(const u32* __restrict__ bad,
                                                   const u32* __restrict__ cnt_dst,
                                                   const u32* __restrict__ cnt_src,
                                                   u32* __restrict__ scal) {
  int wv = threadIdx.x >> 6, ln = threadIdx.x & 63;
  int n = blockIdx.x * 16 + wv;                 // 256 blocks x 16 waves = 4096 rows
  const u32* row = bad + (u32)n * NODE_BM_WORDS;
  u32 sum = 0;
#pragma unroll
  for (int h = 0; h < 2; ++h) {
    int w = ln + h * 64;
    u32 bits = row[w];
    while (bits) { int b = __ffs(bits) - 1; sum += cnt_dst[(w << 5) + b]; bits &= bits - 1; }
  }
#pragma unroll
  for (int off = 32; off > 0; off >>= 1) sum += __shfl_down(sum, off, 64);
  __shared__ u32 part[16];
  if (ln == 0) part[wv] = ((u32)E_CNT - sum) * cnt_src[n];
  __syncthreads();
  if (threadIdx.x == 0) {
    u32 tot = 0;
#pragma unroll
    for (int k = 0; k < 16; ++k) tot += part[k];
    atomicAdd(&scal[0], tot);
    __threadfence();
    if (atomicAdd(&scal[1], 1u) == 255u) {      // last of 256 blocks
      u32 nn = atomicAdd(&scal[0], 0u);         // coherent read
      u32 ratio = nn >> 13;                     // num_neg // E
      float kp = 2.0f / (float)ratio;           // f32(K)/f32(ratio), as JAX
      // u = m*2^-23 exact; u < kp  <=>  m < T = ceil(kp*2^23)  <=>  bits < T<<9
      u32 T = (u32)ceil((double)kp * 8388608.0);
      u32 T9 = (T >= (1u << 23)) ? 0xFFFFFFFFu : (T << 9);
      atomicExch(&scal[2], T9);
    }
  }
}

// --- K3': threefry sampling + ordered compaction fused via decoupled lookback.
// Ordered ticket (scal[3]) assigns tiles in start order -> lookback on earlier
// tickets can never deadlock (they started first, never wait on later blocks).
// Descriptor: flag(hi32): 0=empty 1=aggregate 2=inclusive; value(lo32)=count.
__global__ void __launch_bounds__(1024) k_sample(const int* __restrict__ src,
                                                 const int* __restrict__ dst,
                                                 const u32* __restrict__ bad,
                                                 u32* __restrict__ scal,
                                                 u64* __restrict__ desc,
                                                 int* __restrict__ out) {
  __shared__ u32 sh_cnt[16];
  __shared__ u32 sh_vb;
  __shared__ u32 sh_excl;
  const u32 t = threadIdx.x;
  const u32 wv = t >> 6, ln = t & 63;

  if (t == 0) sh_vb = atomicAdd(&scal[3], 1u);
  __syncthreads();
  const u32 vb = sh_vb;                         // virtual (ordered) block id
  const u32 T9 = scal[2];
  const u32 i0w = vb * 8192u + wv * 512u;       // wave covers 512 consecutive i

  u64 words[8];
  u64 any = 0;
#pragma unroll
  for (int h = 0; h < 2; ++h) {
    u32 i0 = i0w + (u32)h * 256u + ln;
    u32 b0, b1, b2, b3;
    threefry4_0_42(i0, i0 + 64u, i0 + 128u, i0 + 192u, b0, b1, b2, b3);
    u64 m0 = __ballot(b0 < T9);
    u64 m1 = __ballot(b1 < T9);
    u64 m2 = __ballot(b2 < T9);
    u64 m3 = __ballot(b3 < T9);
    words[4 * h]     = m0;
    words[4 * h + 1] = m1;
    words[4 * h + 2] = m2;
    words[4 * h + 3] = m3;
    any |= m0 | m1 | m2 | m3;
  }
  if (any) {  // rare: refine kept lanes against bad bitmap
#pragma unroll
    for (int k = 0; k < 8; ++k) {
      if (words[k]) {
        u32 i = i0w + (u32)k * 64u + ln;
        bool kp = (words[k] >> ln) & 1ull;
        if (kp) {
          u32 n = (u32)src[i >> 13]; u32 v = (u32)dst[i & 8191];
          kp = ((bad[n * NODE_BM_WORDS + (v >> 5)] >> (v & 31)) & 1u) == 0u;
        }
        words[k] = __ballot(kp);
      }
    }
  }
  u32 wcnt = 0;
#pragma unroll
  for (int k = 0; k < 8; ++k) wcnt += (u32)__popcll(words[k]);
  if (ln == 0) sh_cnt[wv] = wcnt;
  __syncthreads();

  // ---- wave 0: publish aggregate, lookback for exclusive prefix ----
  if (wv == 0) {
    u32 tot = 0;
#pragma unroll
    for (int k = 0; k < 16; ++k) tot += sh_cnt[k];
    if (ln == 0) atomicExch(&desc[vb], (1ull << 32) | (u64)tot);
    u32 excl = 0;
    if (vb != 0u) {
      int base = (int)vb - 1;
      for (;;) {
        int idx = base - (int)ln;
        u64 d = (idx >= 0) ? atomicAdd(&desc[idx], 0ull) : (2ull << 32);
        u32 flag = (u32)(d >> 32);
        u64 incl_m = __ballot(flag == 2u);
        u64 nr_m   = __ballot(flag == 0u);
        int fi = incl_m ? (__ffsll((unsigned long long)incl_m) - 1) : 64;
        int fn = nr_m   ? (__ffsll((unsigned long long)nr_m)   - 1) : 64;
        if (fn < fi) { __builtin_amdgcn_s_sleep(1); continue; }  // unready closer than any inclusive
        u32 contrib = ((int)ln <= fi) ? (u32)d : 0u;  // lanes<fi: aggregates; lane fi: inclusive(or 0)
#pragma unroll
        for (int off = 32; off > 0; off >>= 1) contrib += __shfl_down(contrib, off, 64);
        excl += __shfl(contrib, 0, 64);
        if (fi < 64) break;                     // inclusive found -> done
        base -= 64;                             // whole window aggregates -> slide
        if (base < 0) break;
      }
    }
    if (ln == 0) {
      atomicExch(&desc[vb], (2ull << 32) | (u64)(excl + tot));
      sh_excl = excl;
    }
  }
  __syncthreads();

  // ---- lane-parallel ordered writes (mbcnt prefix ranks, no serial ffs) ----
  u32 wexcl = sh_excl;
#pragma unroll
  for (int k = 0; k < 16; ++k) wexcl += ((u32)k < wv) ? sh_cnt[k] : 0u;
  u32 rbase = wexcl;
#pragma unroll
  for (int k = 0; k < 8; ++k) {
    u64 wk = words[k];
    if ((wk >> ln) & 1ull) {
      u32 rank = rbase + mbcnt64(wk);
      if (rank < OUT_K) {
        u32 i = i0w + (u32)k * 64u + ln;
        out[rank]         = src[i >> 13];
        out[OUT_K + rank] = dst[i & 8191];
      }
    }
    rbase += (u32)__popcll(wk);
  }

  // ---- last ticket knows the grand total: write padding (fill=(src0,dst0)) ----
  if (vb == (u32)(N_BLKS - 1)) {
    u32 tot = 0;
#pragma unroll
    for (int k = 0; k < 16; ++k) tot += sh_cnt[k];
    u32 total = sh_excl + tot;
    int s0 = src[0], d0 = dst[0];
    for (u32 p = total + t; p < OUT_K; p += 1024u) {
      out[p] = s0; out[OUT_K + p] = d0;
    }
  }
}

extern "C" void kernel_launch(void* const* d_in, const int* in_sizes, int n_in,
                              void* d_out, int out_size, void* d_ws, size_t ws_size,
                              hipStream_t stream) {
  const int* src = (const int*)d_in[1];  // edge_src
  const int* dst = (const int*)d_in[2];  // edge_dst  (node_feature d_in[0] unused)
  int* out = (int*)d_out;                // [edge_src_neg(16384) | edge_dst_neg(16384)]
  char* ws = (char*)d_ws;

  u32* bad     = (u32*)(ws + OFF_BAD);
  u32* cnt_dst = (u32*)(ws + OFF_CNT_DST);
  u32* cnt_src = (u32*)(ws + OFF_CNT_SRC);
  u32* scal    = (u32*)(ws + OFF_SCALARS);
  u64* desc    = (u64*)(ws + OFF_DESC);

  hipMemsetAsync(ws, 0, ZERO_BYTES, stream);
  k_build<<<E_CNT / 256, 256, 0, stream>>>(src, dst, bad, cnt_dst, cnt_src);
  k_rowcount<<<N_CNT / 16, 1024, 0, stream>>>(bad, cnt_dst, cnt_src, scal);
  k_sample<<<N_BLKS, 1024, 0, stream>>>(src, dst, bad, scal, desc, out);
}